// Round 6
// baseline (355.989 us; speedup 1.0000x reference)
//
#include <hip/hip_runtime.h>
#include <math.h>

#define NODES 50000
#define NEDGES 800000
#define TOT_E (NEDGES + NODES)
#define SCAN_B 256
#define SCAN_NB ((NODES + SCAN_B - 1) / SCAN_B)

typedef __attribute__((ext_vector_type(8))) short short8v;
typedef __attribute__((ext_vector_type(4))) float f32x4;

static __device__ __forceinline__ float lrelu(float z) {
  return z > 0.f ? z : 0.2f * z;
}
static __device__ __forceinline__ float b2f(ushort u) {
  union { uint i; float f; } v; v.i = ((uint)u) << 16; return v.f;
}
static __device__ __forceinline__ ushort f2b(float f) {
  union { float f; uint i; } v; v.f = f;
  uint r = v.i + 0x7fff + ((v.i >> 16) & 1);
  return (ushort)(r >> 16);
}

// ---------------- CSR build ----------------
__global__ void k_hist(const int* __restrict__ dst, int* __restrict__ counts) {
  int stride = gridDim.x * blockDim.x;
  for (int i = blockIdx.x * blockDim.x + threadIdx.x; i < TOT_E; i += stride) {
    int d = (i < NEDGES) ? dst[i] : (i - NEDGES);
    atomicAdd(&counts[d], 1);
  }
}

__global__ __launch_bounds__(SCAN_B) void k_scan_red(const int* __restrict__ counts,
                                                     int* __restrict__ bsum) {
  __shared__ int sm[SCAN_B];
  int idx = blockIdx.x * SCAN_B + threadIdx.x;
  int v = (idx < NODES) ? counts[idx] : 0;
  sm[threadIdx.x] = v;
  __syncthreads();
  for (int off = SCAN_B / 2; off > 0; off >>= 1) {
    if (threadIdx.x < off) sm[threadIdx.x] += sm[threadIdx.x + off];
    __syncthreads();
  }
  if (threadIdx.x == 0) bsum[blockIdx.x] = sm[0];
}

__global__ __launch_bounds__(256) void k_scan_part(const int* __restrict__ bsum,
                                                   int* __restrict__ bpre) {
  __shared__ int sm[256];
  int tid = threadIdx.x;
  int v = (tid < SCAN_NB) ? bsum[tid] : 0;
  sm[tid] = v;
  __syncthreads();
  for (int off = 1; off < 256; off <<= 1) {
    int t = (tid >= off) ? sm[tid - off] : 0;
    __syncthreads();
    sm[tid] += t;
    __syncthreads();
  }
  if (tid < SCAN_NB) bpre[tid] = sm[tid] - v;  // exclusive
}

__global__ __launch_bounds__(SCAN_B) void k_scan_emit(const int* __restrict__ counts,
    const int* __restrict__ bpre, int* __restrict__ offs, int* __restrict__ cur) {
  __shared__ int sm[SCAN_B];
  int idx = blockIdx.x * SCAN_B + threadIdx.x;
  int tid = threadIdx.x;
  int v = (idx < NODES) ? counts[idx] : 0;
  sm[tid] = v;
  __syncthreads();
  for (int off = 1; off < SCAN_B; off <<= 1) {
    int t = (tid >= off) ? sm[tid - off] : 0;
    __syncthreads();
    sm[tid] += t;
    __syncthreads();
  }
  int base = bpre[blockIdx.x];
  int excl = base + sm[tid] - v;
  if (idx < NODES) { offs[idx] = excl; cur[idx] = excl; }
  if (idx == NODES - 1) offs[NODES] = excl + v;
}

__global__ void k_scatter(const int* __restrict__ src, const int* __restrict__ dst,
                          int* __restrict__ cur, int* __restrict__ ssrc) {
  int stride = gridDim.x * blockDim.x;
  for (int i = blockIdx.x * blockDim.x + threadIdx.x; i < TOT_E; i += stride) {
    int s, d;
    if (i < NEDGES) { s = src[i]; d = dst[i]; } else { s = i - NEDGES; d = s; }
    int pos = atomicAdd(&cur[d], 1);
    ssrc[pos] = s;
  }
}

// ---------------- casts / packing ----------------
__global__ void k_cast4(const float* __restrict__ X, ushort* __restrict__ Xb, int total4) {
  int stride = gridDim.x * blockDim.x;
  for (int i = blockIdx.x * blockDim.x + threadIdx.x; i < total4; i += stride) {
    float4 v = *(const float4*)&X[i * 4];
    ushort4 o;
    o.x = f2b(v.x); o.y = f2b(v.y); o.z = f2b(v.z); o.w = f2b(v.w);
    *(ushort4*)&Xb[i * 4] = o;
  }
}

// Bpack[kf][nf][lane][8] = B[kf*32 + (lane>>4)*8 + i][nf*16 + (lane&15)]
__global__ void k_packB(const float* __restrict__ W, ushort* __restrict__ Bp,
                        int N, int NF, int total) {
  int idx = blockIdx.x * blockDim.x + threadIdx.x;
  if (idx >= total) return;
  int i = idx & 7;
  int lane = (idx >> 3) & 63;
  int rem = idx >> 9;
  int nf = rem % NF;
  int kf = rem / NF;
  int k = kf * 32 + (lane >> 4) * 8 + i;
  int col = nf * 16 + (lane & 15);
  float v = (col < N) ? W[(size_t)k * N + col] : 0.f;
  Bp[idx] = f2b(v);
}

// ---------------- register-resident-B MFMA GEMM + fused logits ----------------
template<int KF, int NFW, int CG, int HEADS, int NF_TOT>
__global__ __launch_bounds__(256, 2) void k_gemm_reg(
    const ushort* __restrict__ A, const ushort* __restrict__ Bp,
    ushort* __restrict__ H, const float* __restrict__ a_s, const float* __restrict__ a_d,
    float* __restrict__ al_s, float* __restrict__ al_d, int M, int N, int K) {
  int wave = (blockIdx.x * blockDim.x + threadIdx.x) >> 6;
  int lane = threadIdx.x & 63;
  int lg = lane >> 4;
  int lr = lane & 15;
  int total_waves = (gridDim.x * blockDim.x) >> 6;
  int wpc = total_waves / CG;
  int cg = wave / wpc;
  int mslot = wave - cg * wpc;
  if (cg >= CG) return;

  short8v b[KF][NFW];
#pragma unroll
  for (int kf = 0; kf < KF; ++kf)
#pragma unroll
    for (int n = 0; n < NFW; ++n)
      b[kf][n] = *(const short8v*)(Bp + ((size_t)(kf * NF_TOT + cg * NFW + n) * 64 + lane) * 8);

  float asc[NFW], adc[NFW];
#pragma unroll
  for (int n = 0; n < NFW; ++n) {
    int col = (cg * NFW + n) * 16 + lr;
    bool ok = col < N;
    asc[n] = ok ? a_s[col] : 0.f;
    adc[n] = ok ? a_d[col] : 0.f;
  }

  int nstrips = M >> 4;
  for (int strip = mslot; strip < nstrips; strip += wpc) {
    const ushort* arow = A + (size_t)(strip * 16 + lr) * K + lg * 8;
    short8v a[KF];
#pragma unroll
    for (int kf = 0; kf < KF; ++kf) a[kf] = *(const short8v*)(arow + kf * 32);
    f32x4 acc[NFW];
#pragma unroll
    for (int n = 0; n < NFW; ++n) acc[n] = (f32x4){0.f, 0.f, 0.f, 0.f};
#pragma unroll
    for (int kf = 0; kf < KF; ++kf)
#pragma unroll
      for (int n = 0; n < NFW; ++n)
        acc[n] = __builtin_amdgcn_mfma_f32_16x16x32_bf16(a[kf], b[kf][n], acc[n], 0, 0, 0);

#pragma unroll
    for (int n = 0; n < NFW; ++n) {
      int col = (cg * NFW + n) * 16 + lr;
      if (col < N) {
#pragma unroll
        for (int r = 0; r < 4; ++r) {
          int row = strip * 16 + lg * 4 + r;
          H[(size_t)row * N + col] = f2b(acc[n][r]);
        }
      }
    }

    float ps[4], pd[4];
#pragma unroll
    for (int r = 0; r < 4; ++r) {
      float s = 0.f, d = 0.f;
#pragma unroll
      for (int n = 0; n < NFW; ++n) {
        s += acc[n][r] * asc[n];
        d += acc[n][r] * adc[n];
      }
      ps[r] = s; pd[r] = d;
    }
#pragma unroll
    for (int off = 1; off <= 8; off <<= 1)
#pragma unroll
      for (int t = 0; t < 4; ++t) {
        ps[t] += __shfl_xor(ps[t], off);
        pd[t] += __shfl_xor(pd[t], off);
      }
    if (lr < 4) {
      int row = strip * 16 + lg * 4 + lr;
      if (HEADS == 4) {
        al_s[row * 4 + cg] = ps[lr];
        al_d[row * 4 + cg] = pd[lr];
      } else {
        al_s[row] = ps[lr];
        al_d[row] = pd[lr];
      }
    }
  }
}

// ---------------- aggregation: wave per dst node ----------------
// layers 0/1: H=4, C=64. Pass A: 64-edge-parallel alpha stats.
// Pass B: 4 edges in flight, alphas via shfl, lane covers 16 channels.
__global__ __launch_bounds__(256) void k_agg4(const ushort* __restrict__ hb,
    const float* __restrict__ al_s, const float* __restrict__ al_d,
    const int* __restrict__ offs, const int* __restrict__ ssrc,
    const float* __restrict__ bias, ushort* __restrict__ outb) {
  int wid = (blockIdx.x * blockDim.x + threadIdx.x) >> 6;
  if (wid >= NODES) return;
  int lane = threadIdx.x & 63;
  int beg = offs[wid], end = offs[wid + 1];
  float4 ald4 = *(const float4*)&al_d[wid * 4];

  // pass A: per-lane online stats (lane-strided edges, all loads parallel)
  float m[4], s[4];
#pragma unroll
  for (int h = 0; h < 4; ++h) { m[h] = -1e30f; s[h] = 0.f; }
  for (int i = beg + lane; i < end; i += 64) {
    int sv = ssrc[i];
    float4 a4 = *(const float4*)&al_s[sv * 4];
    float z0 = lrelu(a4.x + ald4.x), z1 = lrelu(a4.y + ald4.y);
    float z2 = lrelu(a4.z + ald4.z), z3 = lrelu(a4.w + ald4.w);
    float z[4] = {z0, z1, z2, z3};
#pragma unroll
    for (int h = 0; h < 4; ++h) {
      if (z[h] > m[h]) { s[h] = s[h] * __expf(m[h] - z[h]) + 1.f; m[h] = z[h]; }
      else s[h] += __expf(z[h] - m[h]);
    }
  }
#pragma unroll
  for (int off = 1; off <= 32; off <<= 1) {
#pragma unroll
    for (int h = 0; h < 4; ++h) {
      float mo = __shfl_xor(m[h], off), so = __shfl_xor(s[h], off);
      float mn = fmaxf(m[h], mo);
      s[h] = s[h] * __expf(m[h] - mn) + so * __expf(mo - mn);
      m[h] = mn;
    }
  }
  float inv[4];
#pragma unroll
  for (int h = 0; h < 4; ++h) inv[h] = 1.f / s[h];

  // pass B: gather; lane = (edge quad q, channel-16-group c)
  int q = lane >> 4;
  int c = lane & 15;
  int hsel = c >> 2;
  float facc[16];
#pragma unroll
  for (int j = 0; j < 16; ++j) facc[j] = 0.f;

  for (int cb = beg; cb < end; cb += 64) {
    int cnt = min(64, end - cb);
    float av0 = 0.f, av1 = 0.f, av2 = 0.f, av3 = 0.f;
    int myidx = 0;
    if (lane < cnt) {
      myidx = ssrc[cb + lane];
      float4 a4 = *(const float4*)&al_s[myidx * 4];
      av0 = __expf(lrelu(a4.x + ald4.x) - m[0]) * inv[0];
      av1 = __expf(lrelu(a4.y + ald4.y) - m[1]) * inv[1];
      av2 = __expf(lrelu(a4.z + ald4.z) - m[2]) * inv[2];
      av3 = __expf(lrelu(a4.w + ald4.w) - m[3]) * inv[3];
    }
    for (int e = 0; e < cnt; e += 4) {
      int eq = e + q;
      int sv = __shfl(myidx, eq);
      float a0 = __shfl(av0, eq), a1 = __shfl(av1, eq);
      float a2 = __shfl(av2, eq), a3 = __shfl(av3, eq);
      float al = hsel == 0 ? a0 : (hsel == 1 ? a1 : (hsel == 2 ? a2 : a3));
      if (eq < cnt) {
        const ushort* hr = hb + (size_t)sv * 256 + c * 16;
        short8v v0 = *(const short8v*)hr;
        short8v v1 = *(const short8v*)(hr + 8);
#pragma unroll
        for (int j = 0; j < 8; ++j) facc[j] += al * b2f((ushort)v0[j]);
#pragma unroll
        for (int j = 0; j < 8; ++j) facc[j + 8] += al * b2f((ushort)v1[j]);
      }
    }
  }
#pragma unroll
  for (int j = 0; j < 16; ++j) {
    facc[j] += __shfl_xor(facc[j], 16);
    facc[j] += __shfl_xor(facc[j], 32);
  }
  if (q == 0) {
    short8v o0, o1;
#pragma unroll
    for (int j = 0; j < 8; ++j) {
      float v = facc[j] + bias[c * 16 + j];
      o0[j] = (short)f2b(v > 0.f ? v : __expf(v) - 1.f);
      float w = facc[j + 8] + bias[c * 16 + 8 + j];
      o1[j] = (short)f2b(w > 0.f ? w : __expf(w) - 1.f);
    }
    *(short8v*)(outb + (size_t)wid * 256 + c * 16) = o0;
    *(short8v*)(outb + (size_t)wid * 256 + c * 16 + 8) = o1;
  }
}

// layer 2: H=1, C=40; same structure, single head
__global__ __launch_bounds__(256) void k_agg1(const ushort* __restrict__ hb,
    const float* __restrict__ al_s, const float* __restrict__ al_d,
    const int* __restrict__ offs, const int* __restrict__ ssrc,
    const float* __restrict__ bias, float* __restrict__ out) {
  int wid = (blockIdx.x * blockDim.x + threadIdx.x) >> 6;
  if (wid >= NODES) return;
  int lane = threadIdx.x & 63;
  int beg = offs[wid], end = offs[wid + 1];
  float ald = al_d[wid];

  float m = -1e30f, s = 0.f;
  for (int i = beg + lane; i < end; i += 64) {
    float z = lrelu(al_s[ssrc[i]] + ald);
    if (z > m) { s = s * __expf(m - z) + 1.f; m = z; }
    else s += __expf(z - m);
  }
#pragma unroll
  for (int off = 1; off <= 32; off <<= 1) {
    float mo = __shfl_xor(m, off), so = __shfl_xor(s, off);
    float mn = fmaxf(m, mo);
    s = s * __expf(m - mn) + so * __expf(mo - mn);
    m = mn;
  }
  float inv = 1.f / s;

  int q = lane >> 4;
  int cq = lane & 15;
  bool act = cq < 10;
  float acc[4] = {0.f, 0.f, 0.f, 0.f};
  for (int cb = beg; cb < end; cb += 64) {
    int cnt = min(64, end - cb);
    float av = 0.f;
    int myidx = 0;
    if (lane < cnt) {
      myidx = ssrc[cb + lane];
      av = __expf(lrelu(al_s[myidx] + ald) - m) * inv;
    }
    for (int e = 0; e < cnt; e += 4) {
      int eq = e + q;
      int sv = __shfl(myidx, eq);
      float al = __shfl(av, eq);
      if (eq < cnt && act) {
        ushort4 hv = *(const ushort4*)&hb[(size_t)sv * 40 + cq * 4];
        acc[0] += al * b2f(hv.x); acc[1] += al * b2f(hv.y);
        acc[2] += al * b2f(hv.z); acc[3] += al * b2f(hv.w);
      }
    }
  }
#pragma unroll
  for (int j = 0; j < 4; ++j) {
    acc[j] += __shfl_xor(acc[j], 16);
    acc[j] += __shfl_xor(acc[j], 32);
  }
  float v[4];
  float mm = -1e30f;
  if (act) {
#pragma unroll
    for (int j = 0; j < 4; ++j) {
      v[j] = acc[j] + bias[cq * 4 + j];
      mm = fmaxf(mm, v[j]);
    }
  }
#pragma unroll
  for (int off = 1; off <= 8; off <<= 1) mm = fmaxf(mm, __shfl_xor(mm, off));
  float se = 0.f;
  if (act) {
#pragma unroll
    for (int j = 0; j < 4; ++j) se += __expf(v[j] - mm);
  }
#pragma unroll
  for (int off = 1; off <= 8; off <<= 1) se += __shfl_xor(se, off);
  if (act && q == 0) {
    float lse = mm + __logf(se);
    float4 o;
    o.x = v[0] - lse; o.y = v[1] - lse; o.z = v[2] - lse; o.w = v[3] - lse;
    *(float4*)&out[(size_t)wid * 40 + cq * 4] = o;
  }
}

// ---------------- launch ----------------
extern "C" void kernel_launch(void* const* d_in, const int* in_sizes, int n_in,
                              void* d_out, int out_size, void* d_ws, size_t ws_size,
                              hipStream_t stream) {
  const float* x   = (const float*)d_in[0];
  const int*   ei  = (const int*)d_in[1];
  const float* W0  = (const float*)d_in[2];
  const float* as0 = (const float*)d_in[3];
  const float* ad0 = (const float*)d_in[4];
  const float* b0  = (const float*)d_in[5];
  const float* W1  = (const float*)d_in[6];
  const float* as1 = (const float*)d_in[7];
  const float* ad1 = (const float*)d_in[8];
  const float* b1  = (const float*)d_in[9];
  const float* W2  = (const float*)d_in[10];
  const float* as2 = (const float*)d_in[11];
  const float* ad2 = (const float*)d_in[12];
  const float* b2  = (const float*)d_in[13];
  float* out = (float*)d_out;

  char* p = (char*)d_ws;
  auto take = [&](size_t bytes) {
    char* q = p;
    p += (bytes + 255) & ~(size_t)255;
    return (void*)q;
  };
  ushort* xb0 = (ushort*)take((size_t)NODES * 128 * 2);
  ushort* xb1 = (ushort*)take((size_t)NODES * 256 * 2);
  ushort* xb2 = (ushort*)take((size_t)NODES * 256 * 2);
  ushort* hb  = (ushort*)take((size_t)NODES * 256 * 2);
  float* als  = (float*)take((size_t)NODES * 4 * 4);
  float* ald  = (float*)take((size_t)NODES * 4 * 4);
  int* ssrc   = (int*)take((size_t)TOT_E * 4);
  int* offs   = (int*)take((size_t)(NODES + 1) * 4);
  int* cur    = (int*)take((size_t)NODES * 4);
  int* cnt    = (int*)take((size_t)NODES * 4);
  int* bsum   = (int*)take((size_t)SCAN_NB * 4);
  int* bpre   = (int*)take((size_t)SCAN_NB * 4);
  ushort* Bp0 = (ushort*)take((size_t)4 * 16 * 512 * 2);
  ushort* Bp1 = (ushort*)take((size_t)8 * 16 * 512 * 2);
  ushort* Bp2 = (ushort*)take((size_t)8 * 3 * 512 * 2);

  // CSR build (dst-sorted edge list incl. self-loops)
  hipMemsetAsync(cnt, 0, (size_t)NODES * 4, stream);
  k_hist<<<2048, 256, 0, stream>>>(ei + NEDGES, cnt);
  k_scan_red<<<SCAN_NB, SCAN_B, 0, stream>>>(cnt, bsum);
  k_scan_part<<<1, 256, 0, stream>>>(bsum, bpre);
  k_scan_emit<<<SCAN_NB, SCAN_B, 0, stream>>>(cnt, bpre, offs, cur);
  k_scatter<<<2048, 256, 0, stream>>>(ei, ei + NEDGES, cur, ssrc);

  // bf16 casts / weight packs
  k_cast4<<<2048, 256, 0, stream>>>(x, xb0, NODES * 128 / 4);
  {
    int t0 = 4 * 16 * 512;  k_packB<<<(t0 + 255) / 256, 256, 0, stream>>>(W0, Bp0, 256, 16, t0);
    int t1 = 8 * 16 * 512;  k_packB<<<(t1 + 255) / 256, 256, 0, stream>>>(W1, Bp1, 256, 16, t1);
    int t2 = 8 * 3 * 512;   k_packB<<<(t2 + 255) / 256, 256, 0, stream>>>(W2, Bp2, 40, 3, t2);
  }

  int nwb = (NODES * 64 + 255) / 256;       // wave-per-node blocks
  int ggb = 512;                            // gemm grid: 2048 waves

  // layer 0
  k_gemm_reg<4, 4, 4, 4, 16><<<ggb, 256, 0, stream>>>(xb0, Bp0, hb, as0, ad0, als, ald, NODES, 256, 128);
  k_agg4<<<nwb, 256, 0, stream>>>(hb, als, ald, offs, ssrc, b0, xb1);

  // layer 1
  k_gemm_reg<8, 4, 4, 4, 16><<<ggb, 256, 0, stream>>>(xb1, Bp1, hb, as1, ad1, als, ald, NODES, 256, 256);
  k_agg4<<<nwb, 256, 0, stream>>>(hb, als, ald, offs, ssrc, b1, xb2);

  // layer 2
  k_gemm_reg<8, 3, 1, 1, 3><<<ggb, 256, 0, stream>>>(xb2, Bp2, hb, as2, ad2, als, ald, NODES, 40, 256);
  k_agg1<<<nwb, 256, 0, stream>>>(hb, als, ald, offs, ssrc, b2, out);
}

// Round 7
// 331.405 us; speedup vs baseline: 1.0742x; 1.0742x over previous
//
#include <hip/hip_runtime.h>
#include <math.h>

#define NODES 50000
#define NEDGES 800000
#define TOT_E (NEDGES + NODES)
#define SCAN_B 256
#define SCAN_NB ((NODES + SCAN_B - 1) / SCAN_B)

typedef __attribute__((ext_vector_type(8))) short short8v;
typedef __attribute__((ext_vector_type(4))) float f32x4;

static __device__ __forceinline__ float lrelu(float z) {
  return z > 0.f ? z : 0.2f * z;
}
static __device__ __forceinline__ float b2f(ushort u) {
  union { uint i; float f; } v; v.i = ((uint)u) << 16; return v.f;
}
static __device__ __forceinline__ ushort f2b(float f) {
  union { float f; uint i; } v; v.f = f;
  uint r = v.i + 0x7fff + ((v.i >> 16) & 1);
  return (ushort)(r >> 16);
}
// wave-local LDS fence: order + drain ds ops within one wave (no __syncthreads:
// waves in a block have divergent trip counts)
static __device__ __forceinline__ void wave_lds_fence() {
  __builtin_amdgcn_wave_barrier();
  asm volatile("s_waitcnt lgkmcnt(0)" ::: "memory");
  __builtin_amdgcn_sched_barrier(0);
}

// ---------------- CSR build ----------------
__global__ void k_hist(const int* __restrict__ dst, int* __restrict__ counts) {
  int stride = gridDim.x * blockDim.x;
  for (int i = blockIdx.x * blockDim.x + threadIdx.x; i < TOT_E; i += stride) {
    int d = (i < NEDGES) ? dst[i] : (i - NEDGES);
    atomicAdd(&counts[d], 1);
  }
}

__global__ __launch_bounds__(SCAN_B) void k_scan_red(const int* __restrict__ counts,
                                                     int* __restrict__ bsum) {
  __shared__ int sm[SCAN_B];
  int idx = blockIdx.x * SCAN_B + threadIdx.x;
  int v = (idx < NODES) ? counts[idx] : 0;
  sm[threadIdx.x] = v;
  __syncthreads();
  for (int off = SCAN_B / 2; off > 0; off >>= 1) {
    if (threadIdx.x < off) sm[threadIdx.x] += sm[threadIdx.x + off];
    __syncthreads();
  }
  if (threadIdx.x == 0) bsum[blockIdx.x] = sm[0];
}

__global__ __launch_bounds__(256) void k_scan_part(const int* __restrict__ bsum,
                                                   int* __restrict__ bpre) {
  __shared__ int sm[256];
  int tid = threadIdx.x;
  int v = (tid < SCAN_NB) ? bsum[tid] : 0;
  sm[tid] = v;
  __syncthreads();
  for (int off = 1; off < 256; off <<= 1) {
    int t = (tid >= off) ? sm[tid - off] : 0;
    __syncthreads();
    sm[tid] += t;
    __syncthreads();
  }
  if (tid < SCAN_NB) bpre[tid] = sm[tid] - v;  // exclusive
}

__global__ __launch_bounds__(SCAN_B) void k_scan_emit(const int* __restrict__ counts,
    const int* __restrict__ bpre, int* __restrict__ offs, int* __restrict__ cur) {
  __shared__ int sm[SCAN_B];
  int idx = blockIdx.x * SCAN_B + threadIdx.x;
  int tid = threadIdx.x;
  int v = (idx < NODES) ? counts[idx] : 0;
  sm[tid] = v;
  __syncthreads();
  for (int off = 1; off < SCAN_B; off <<= 1) {
    int t = (tid >= off) ? sm[tid - off] : 0;
    __syncthreads();
    sm[tid] += t;
    __syncthreads();
  }
  int base = bpre[blockIdx.x];
  int excl = base + sm[tid] - v;
  if (idx < NODES) { offs[idx] = excl; cur[idx] = excl; }
  if (idx == NODES - 1) offs[NODES] = excl + v;
}

__global__ void k_scatter(const int* __restrict__ src, const int* __restrict__ dst,
                          int* __restrict__ cur, int* __restrict__ ssrc) {
  int stride = gridDim.x * blockDim.x;
  for (int i = blockIdx.x * blockDim.x + threadIdx.x; i < TOT_E; i += stride) {
    int s, d;
    if (i < NEDGES) { s = src[i]; d = dst[i]; } else { s = i - NEDGES; d = s; }
    int pos = atomicAdd(&cur[d], 1);
    ssrc[pos] = s;
  }
}

// ---------------- casts / packing ----------------
__global__ void k_cast4(const float* __restrict__ X, ushort* __restrict__ Xb, int total4) {
  int stride = gridDim.x * blockDim.x;
  for (int i = blockIdx.x * blockDim.x + threadIdx.x; i < total4; i += stride) {
    float4 v = *(const float4*)&X[i * 4];
    ushort4 o;
    o.x = f2b(v.x); o.y = f2b(v.y); o.z = f2b(v.z); o.w = f2b(v.w);
    *(ushort4*)&Xb[i * 4] = o;
  }
}

// Bpack[kf][nf][lane][8] = B[kf*32 + (lane>>4)*8 + i][nf*16 + (lane&15)]
__global__ void k_packB(const float* __restrict__ W, ushort* __restrict__ Bp,
                        int N, int NF, int total) {
  int idx = blockIdx.x * blockDim.x + threadIdx.x;
  if (idx >= total) return;
  int i = idx & 7;
  int lane = (idx >> 3) & 63;
  int rem = idx >> 9;
  int nf = rem % NF;
  int kf = rem / NF;
  int k = kf * 32 + (lane >> 4) * 8 + i;
  int col = nf * 16 + (lane & 15);
  float v = (col < N) ? W[(size_t)k * N + col] : 0.f;
  Bp[idx] = f2b(v);
}

// ---------------- register-resident-B MFMA GEMM + fused logits ----------------
template<int KF, int NFW, int CG, int HEADS, int NF_TOT>
__global__ __launch_bounds__(256, 2) void k_gemm_reg(
    const ushort* __restrict__ A, const ushort* __restrict__ Bp,
    ushort* __restrict__ H, const float* __restrict__ a_s, const float* __restrict__ a_d,
    float* __restrict__ al_s, float* __restrict__ al_d, int M, int N, int K) {
  int wave = (blockIdx.x * blockDim.x + threadIdx.x) >> 6;
  int lane = threadIdx.x & 63;
  int lg = lane >> 4;
  int lr = lane & 15;
  int total_waves = (gridDim.x * blockDim.x) >> 6;
  int wpc = total_waves / CG;
  int cg = wave / wpc;
  int mslot = wave - cg * wpc;
  if (cg >= CG) return;

  short8v b[KF][NFW];
#pragma unroll
  for (int kf = 0; kf < KF; ++kf)
#pragma unroll
    for (int n = 0; n < NFW; ++n)
      b[kf][n] = *(const short8v*)(Bp + ((size_t)(kf * NF_TOT + cg * NFW + n) * 64 + lane) * 8);

  float asc[NFW], adc[NFW];
#pragma unroll
  for (int n = 0; n < NFW; ++n) {
    int col = (cg * NFW + n) * 16 + lr;
    bool ok = col < N;
    asc[n] = ok ? a_s[col] : 0.f;
    adc[n] = ok ? a_d[col] : 0.f;
  }

  int nstrips = M >> 4;
  for (int strip = mslot; strip < nstrips; strip += wpc) {
    const ushort* arow = A + (size_t)(strip * 16 + lr) * K + lg * 8;
    short8v a[KF];
#pragma unroll
    for (int kf = 0; kf < KF; ++kf) a[kf] = *(const short8v*)(arow + kf * 32);
    f32x4 acc[NFW];
#pragma unroll
    for (int n = 0; n < NFW; ++n) acc[n] = (f32x4){0.f, 0.f, 0.f, 0.f};
#pragma unroll
    for (int kf = 0; kf < KF; ++kf)
#pragma unroll
      for (int n = 0; n < NFW; ++n)
        acc[n] = __builtin_amdgcn_mfma_f32_16x16x32_bf16(a[kf], b[kf][n], acc[n], 0, 0, 0);

#pragma unroll
    for (int n = 0; n < NFW; ++n) {
      int col = (cg * NFW + n) * 16 + lr;
      if (col < N) {
#pragma unroll
        for (int r = 0; r < 4; ++r) {
          int row = strip * 16 + lg * 4 + r;
          H[(size_t)row * N + col] = f2b(acc[n][r]);
        }
      }
    }

    float ps[4], pd[4];
#pragma unroll
    for (int r = 0; r < 4; ++r) {
      float s = 0.f, d = 0.f;
#pragma unroll
      for (int n = 0; n < NFW; ++n) {
        s += acc[n][r] * asc[n];
        d += acc[n][r] * adc[n];
      }
      ps[r] = s; pd[r] = d;
    }
#pragma unroll
    for (int off = 1; off <= 8; off <<= 1)
#pragma unroll
      for (int t = 0; t < 4; ++t) {
        ps[t] += __shfl_xor(ps[t], off);
        pd[t] += __shfl_xor(pd[t], off);
      }
    if (lr < 4) {
      int row = strip * 16 + lg * 4 + lr;
      if (HEADS == 4) {
        al_s[row * 4 + cg] = ps[lr];
        al_d[row * 4 + cg] = pd[lr];
      } else {
        al_s[row] = ps[lr];
        al_d[row] = pd[lr];
      }
    }
  }
}

// ---------------- aggregation: wave per dst node ----------------
// layers 0/1: H=4, C=64.
// pass A: 64-edge-parallel online softmax stats (float4 al_s loads).
// pass B: per 64-edge chunk, stash {idx, alpha4} in LDS (computed once per edge),
//         then dual-half gather: lane = (edge parity, channel octet), alphas via
//         broadcast ds_read. No per-edge exp, no per-edge global al_s loads.
__global__ __launch_bounds__(256) void k_agg4(const ushort* __restrict__ hb,
    const float* __restrict__ al_s, const float* __restrict__ al_d,
    const int* __restrict__ offs, const int* __restrict__ ssrc,
    const float* __restrict__ bias, ushort* __restrict__ outb) {
  __shared__ int s_idx[4][64];
  __shared__ float s_al[4][256];
  int w = threadIdx.x >> 6;
  int wid = (blockIdx.x * blockDim.x + threadIdx.x) >> 6;
  if (wid >= NODES) return;
  int lane = threadIdx.x & 63;
  int beg = offs[wid], end = offs[wid + 1];
  float4 ald4 = *(const float4*)&al_d[wid * 4];

  // pass A: stats
  float m[4], s[4];
#pragma unroll
  for (int h = 0; h < 4; ++h) { m[h] = -1e30f; s[h] = 0.f; }
  for (int i = beg + lane; i < end; i += 64) {
    int sv = ssrc[i];
    float4 a4 = *(const float4*)&al_s[sv * 4];
    float z[4] = {lrelu(a4.x + ald4.x), lrelu(a4.y + ald4.y),
                  lrelu(a4.z + ald4.z), lrelu(a4.w + ald4.w)};
#pragma unroll
    for (int h = 0; h < 4; ++h) {
      if (z[h] > m[h]) { s[h] = s[h] * __expf(m[h] - z[h]) + 1.f; m[h] = z[h]; }
      else s[h] += __expf(z[h] - m[h]);
    }
  }
#pragma unroll
  for (int off = 1; off <= 32; off <<= 1) {
#pragma unroll
    for (int h = 0; h < 4; ++h) {
      float mo = __shfl_xor(m[h], off), so = __shfl_xor(s[h], off);
      float mn = fmaxf(m[h], mo);
      s[h] = s[h] * __expf(m[h] - mn) + so * __expf(mo - mn);
      m[h] = mn;
    }
  }
  float inv[4];
#pragma unroll
  for (int h = 0; h < 4; ++h) inv[h] = 1.f / s[h];

  // pass B
  int half = lane >> 5;      // edge parity
  int cl = lane & 31;        // channel octet
  int hh = cl >> 3;          // head of this octet
  float facc[8] = {0.f, 0.f, 0.f, 0.f, 0.f, 0.f, 0.f, 0.f};

  for (int cb = beg; cb < end; cb += 64) {
    int cnt = min(64, end - cb);
    wave_lds_fence();  // prior chunk's reads complete before overwrite
    if (lane < cnt) {
      int sv = ssrc[cb + lane];
      float4 a4 = *(const float4*)&al_s[sv * 4];  // L1-hot from pass A
      float4 al;
      al.x = __expf(lrelu(a4.x + ald4.x) - m[0]) * inv[0];
      al.y = __expf(lrelu(a4.y + ald4.y) - m[1]) * inv[1];
      al.z = __expf(lrelu(a4.z + ald4.z) - m[2]) * inv[2];
      al.w = __expf(lrelu(a4.w + ald4.w) - m[3]) * inv[3];
      s_idx[w][lane] = sv;
      *(float4*)&s_al[w][lane * 4] = al;
    }
    wave_lds_fence();  // writes visible to all lanes of this wave
    int e = half;
    for (; e + 2 < cnt; e += 4) {
      int sv0 = s_idx[w][e], sv1 = s_idx[w][e + 2];
      float a0 = s_al[w][e * 4 + hh];
      float a1 = s_al[w][(e + 2) * 4 + hh];
      short8v hv0 = *(const short8v*)(hb + (size_t)sv0 * 256 + cl * 8);
      short8v hv1 = *(const short8v*)(hb + (size_t)sv1 * 256 + cl * 8);
#pragma unroll
      for (int j = 0; j < 8; ++j) facc[j] += a0 * b2f((ushort)hv0[j]);
#pragma unroll
      for (int j = 0; j < 8; ++j) facc[j] += a1 * b2f((ushort)hv1[j]);
    }
    for (; e < cnt; e += 2) {
      int sv = s_idx[w][e];
      float al = s_al[w][e * 4 + hh];
      short8v hv = *(const short8v*)(hb + (size_t)sv * 256 + cl * 8);
#pragma unroll
      for (int j = 0; j < 8; ++j) facc[j] += al * b2f((ushort)hv[j]);
    }
  }
#pragma unroll
  for (int j = 0; j < 8; ++j) facc[j] += __shfl_xor(facc[j], 32);
  if (half == 0) {
    short8v o;
#pragma unroll
    for (int j = 0; j < 8; ++j) {
      float v = facc[j] + bias[cl * 8 + j];
      o[j] = (short)f2b(v > 0.f ? v : __expf(v) - 1.f);
    }
    *(short8v*)(outb + (size_t)wid * 256 + cl * 8) = o;
  }
}

// layer 2: H=1, C=40; same LDS-staged structure, 4 edges in flight
__global__ __launch_bounds__(256) void k_agg1(const ushort* __restrict__ hb,
    const float* __restrict__ al_s, const float* __restrict__ al_d,
    const int* __restrict__ offs, const int* __restrict__ ssrc,
    const float* __restrict__ bias, float* __restrict__ out) {
  __shared__ int s_idx[4][64];
  __shared__ float s_al[4][64];
  int w = threadIdx.x >> 6;
  int wid = (blockIdx.x * blockDim.x + threadIdx.x) >> 6;
  if (wid >= NODES) return;
  int lane = threadIdx.x & 63;
  int beg = offs[wid], end = offs[wid + 1];
  float ald = al_d[wid];

  float m = -1e30f, s = 0.f;
  for (int i = beg + lane; i < end; i += 64) {
    float z = lrelu(al_s[ssrc[i]] + ald);
    if (z > m) { s = s * __expf(m - z) + 1.f; m = z; }
    else s += __expf(z - m);
  }
#pragma unroll
  for (int off = 1; off <= 32; off <<= 1) {
    float mo = __shfl_xor(m, off), so = __shfl_xor(s, off);
    float mn = fmaxf(m, mo);
    s = s * __expf(m - mn) + so * __expf(mo - mn);
    m = mn;
  }
  float inv = 1.f / s;

  int q = lane >> 4;         // edge quad
  int cq = lane & 15;        // channel quad
  bool act = cq < 10;
  float acc[4] = {0.f, 0.f, 0.f, 0.f};
  for (int cb = beg; cb < end; cb += 64) {
    int cnt = min(64, end - cb);
    wave_lds_fence();
    if (lane < cnt) {
      int sv = ssrc[cb + lane];
      s_idx[w][lane] = sv;
      s_al[w][lane] = __expf(lrelu(al_s[sv] + ald) - m) * inv;
    }
    wave_lds_fence();
    int e = q;
    for (; e + 4 < cnt; e += 8) {
      int sv0 = s_idx[w][e], sv1 = s_idx[w][e + 4];
      float a0 = s_al[w][e], a1 = s_al[w][e + 4];
      if (act) {
        ushort4 hv0 = *(const ushort4*)&hb[(size_t)sv0 * 40 + cq * 4];
        ushort4 hv1 = *(const ushort4*)&hb[(size_t)sv1 * 40 + cq * 4];
        acc[0] += a0 * b2f(hv0.x) + a1 * b2f(hv1.x);
        acc[1] += a0 * b2f(hv0.y) + a1 * b2f(hv1.y);
        acc[2] += a0 * b2f(hv0.z) + a1 * b2f(hv1.z);
        acc[3] += a0 * b2f(hv0.w) + a1 * b2f(hv1.w);
      }
    }
    for (; e < cnt; e += 4) {
      int sv = s_idx[w][e];
      float al = s_al[w][e];
      if (act) {
        ushort4 hv = *(const ushort4*)&hb[(size_t)sv * 40 + cq * 4];
        acc[0] += al * b2f(hv.x); acc[1] += al * b2f(hv.y);
        acc[2] += al * b2f(hv.z); acc[3] += al * b2f(hv.w);
      }
    }
  }
#pragma unroll
  for (int j = 0; j < 4; ++j) {
    acc[j] += __shfl_xor(acc[j], 16);
    acc[j] += __shfl_xor(acc[j], 32);
  }
  float v[4];
  float mm = -1e30f;
  if (act) {
#pragma unroll
    for (int j = 0; j < 4; ++j) {
      v[j] = acc[j] + bias[cq * 4 + j];
      mm = fmaxf(mm, v[j]);
    }
  }
#pragma unroll
  for (int off = 1; off <= 8; off <<= 1) mm = fmaxf(mm, __shfl_xor(mm, off));
  float se = 0.f;
  if (act) {
#pragma unroll
    for (int j = 0; j < 4; ++j) se += __expf(v[j] - mm);
  }
#pragma unroll
  for (int off = 1; off <= 8; off <<= 1) se += __shfl_xor(se, off);
  if (act && q == 0) {
    float lse = mm + __logf(se);
    float4 o;
    o.x = v[0] - lse; o.y = v[1] - lse; o.z = v[2] - lse; o.w = v[3] - lse;
    *(float4*)&out[(size_t)wid * 40 + cq * 4] = o;
  }
}

// ---------------- launch ----------------
extern "C" void kernel_launch(void* const* d_in, const int* in_sizes, int n_in,
                              void* d_out, int out_size, void* d_ws, size_t ws_size,
                              hipStream_t stream) {
  const float* x   = (const float*)d_in[0];
  const int*   ei  = (const int*)d_in[1];
  const float* W0  = (const float*)d_in[2];
  const float* as0 = (const float*)d_in[3];
  const float* ad0 = (const float*)d_in[4];
  const float* b0  = (const float*)d_in[5];
  const float* W1  = (const float*)d_in[6];
  const float* as1 = (const float*)d_in[7];
  const float* ad1 = (const float*)d_in[8];
  const float* b1  = (const float*)d_in[9];
  const float* W2  = (const float*)d_in[10];
  const float* as2 = (const float*)d_in[11];
  const float* ad2 = (const float*)d_in[12];
  const float* b2  = (const float*)d_in[13];
  float* out = (float*)d_out;

  char* p = (char*)d_ws;
  auto take = [&](size_t bytes) {
    char* q = p;
    p += (bytes + 255) & ~(size_t)255;
    return (void*)q;
  };
  ushort* xb0 = (ushort*)take((size_t)NODES * 128 * 2);
  ushort* xb1 = (ushort*)take((size_t)NODES * 256 * 2);
  ushort* xb2 = (ushort*)take((size_t)NODES * 256 * 2);
  ushort* hb  = (ushort*)take((size_t)NODES * 256 * 2);
  float* als  = (float*)take((size_t)NODES * 4 * 4);
  float* ald  = (float*)take((size_t)NODES * 4 * 4);
  int* ssrc   = (int*)take((size_t)TOT_E * 4);
  int* offs   = (int*)take((size_t)(NODES + 1) * 4);
  int* cur    = (int*)take((size_t)NODES * 4);
  int* cnt    = (int*)take((size_t)NODES * 4);
  int* bsum   = (int*)take((size_t)SCAN_NB * 4);
  int* bpre   = (int*)take((size_t)SCAN_NB * 4);
  ushort* Bp0 = (ushort*)take((size_t)4 * 16 * 512 * 2);
  ushort* Bp1 = (ushort*)take((size_t)8 * 16 * 512 * 2);
  ushort* Bp2 = (ushort*)take((size_t)8 * 3 * 512 * 2);

  // CSR build (dst-sorted edge list incl. self-loops)
  hipMemsetAsync(cnt, 0, (size_t)NODES * 4, stream);
  k_hist<<<2048, 256, 0, stream>>>(ei + NEDGES, cnt);
  k_scan_red<<<SCAN_NB, SCAN_B, 0, stream>>>(cnt, bsum);
  k_scan_part<<<1, 256, 0, stream>>>(bsum, bpre);
  k_scan_emit<<<SCAN_NB, SCAN_B, 0, stream>>>(cnt, bpre, offs, cur);
  k_scatter<<<2048, 256, 0, stream>>>(ei, ei + NEDGES, cur, ssrc);

  // bf16 casts / weight packs
  k_cast4<<<2048, 256, 0, stream>>>(x, xb0, NODES * 128 / 4);
  {
    int t0 = 4 * 16 * 512;  k_packB<<<(t0 + 255) / 256, 256, 0, stream>>>(W0, Bp0, 256, 16, t0);
    int t1 = 8 * 16 * 512;  k_packB<<<(t1 + 255) / 256, 256, 0, stream>>>(W1, Bp1, 256, 16, t1);
    int t2 = 8 * 3 * 512;   k_packB<<<(t2 + 255) / 256, 256, 0, stream>>>(W2, Bp2, 40, 3, t2);
  }

  int nwb = (NODES * 64 + 255) / 256;       // wave-per-node blocks
  int ggb = 512;                            // gemm grid: 2048 waves

  // layer 0
  k_gemm_reg<4, 4, 4, 4, 16><<<ggb, 256, 0, stream>>>(xb0, Bp0, hb, as0, ad0, als, ald, NODES, 256, 128);
  k_agg4<<<nwb, 256, 0, stream>>>(hb, als, ald, offs, ssrc, b0, xb1);

  // layer 1
  k_gemm_reg<8, 4, 4, 4, 16><<<ggb, 256, 0, stream>>>(xb1, Bp1, hb, as1, ad1, als, ald, NODES, 256, 256);
  k_agg4<<<nwb, 256, 0, stream>>>(hb, als, ald, offs, ssrc, b1, xb2);

  // layer 2
  k_gemm_reg<8, 3, 1, 1, 3><<<ggb, 256, 0, stream>>>(xb2, Bp2, hb, as2, ad2, als, ald, NODES, 40, 256);
  k_agg1<<<nwb, 256, 0, stream>>>(hb, als, ald, offs, ssrc, b2, out);
}

// Round 8
// 328.702 us; speedup vs baseline: 1.0830x; 1.0082x over previous
//
#include <hip/hip_runtime.h>
#include <hip/hip_fp16.h>
#include <math.h>

#define NODES 50000
#define NEDGES 800000
#define TOT_E (NEDGES + NODES)
#define SCAN_B 256
#define SCAN_NB ((NODES + SCAN_B - 1) / SCAN_B)

typedef __attribute__((ext_vector_type(8))) _Float16 half8v;
typedef __attribute__((ext_vector_type(4))) float f32x4;

union U2H { uint u; __half2 h; };

static __device__ __forceinline__ float lrelu(float z) {
  return z > 0.f ? z : 0.2f * z;
}
static __device__ __forceinline__ ushort f2h(float f) {
  __half h = __float2half_rn(f);
  return *reinterpret_cast<ushort*>(&h);
}
// wave-local LDS fence (no __syncthreads: waves have divergent trip counts)
static __device__ __forceinline__ void wave_lds_fence() {
  __builtin_amdgcn_wave_barrier();
  asm volatile("s_waitcnt lgkmcnt(0)" ::: "memory");
  __builtin_amdgcn_sched_barrier(0);
}

// ---------------- CSR build ----------------
__global__ void k_hist(const int* __restrict__ dst, int* __restrict__ counts) {
  int stride = gridDim.x * blockDim.x;
  for (int i = blockIdx.x * blockDim.x + threadIdx.x; i < TOT_E; i += stride) {
    int d = (i < NEDGES) ? dst[i] : (i - NEDGES);
    atomicAdd(&counts[d], 1);
  }
}

__global__ __launch_bounds__(SCAN_B) void k_scan_red(const int* __restrict__ counts,
                                                     int* __restrict__ bsum) {
  __shared__ int sm[SCAN_B];
  int idx = blockIdx.x * SCAN_B + threadIdx.x;
  int v = (idx < NODES) ? counts[idx] : 0;
  sm[threadIdx.x] = v;
  __syncthreads();
  for (int off = SCAN_B / 2; off > 0; off >>= 1) {
    if (threadIdx.x < off) sm[threadIdx.x] += sm[threadIdx.x + off];
    __syncthreads();
  }
  if (threadIdx.x == 0) bsum[blockIdx.x] = sm[0];
}

__global__ __launch_bounds__(256) void k_scan_part(const int* __restrict__ bsum,
                                                   int* __restrict__ bpre) {
  __shared__ int sm[256];
  int tid = threadIdx.x;
  int v = (tid < SCAN_NB) ? bsum[tid] : 0;
  sm[tid] = v;
  __syncthreads();
  for (int off = 1; off < 256; off <<= 1) {
    int t = (tid >= off) ? sm[tid - off] : 0;
    __syncthreads();
    sm[tid] += t;
    __syncthreads();
  }
  if (tid < SCAN_NB) bpre[tid] = sm[tid] - v;  // exclusive
}

__global__ __launch_bounds__(SCAN_B) void k_scan_emit(const int* __restrict__ counts,
    const int* __restrict__ bpre, int* __restrict__ offs, int* __restrict__ cur) {
  __shared__ int sm[SCAN_B];
  int idx = blockIdx.x * SCAN_B + threadIdx.x;
  int tid = threadIdx.x;
  int v = (idx < NODES) ? counts[idx] : 0;
  sm[tid] = v;
  __syncthreads();
  for (int off = 1; off < SCAN_B; off <<= 1) {
    int t = (tid >= off) ? sm[tid - off] : 0;
    __syncthreads();
    sm[tid] += t;
    __syncthreads();
  }
  int base = bpre[blockIdx.x];
  int excl = base + sm[tid] - v;
  if (idx < NODES) { offs[idx] = excl; cur[idx] = excl; }
  if (idx == NODES - 1) offs[NODES] = excl + v;
}

__global__ void k_scatter(const int* __restrict__ src, const int* __restrict__ dst,
                          int* __restrict__ cur, int* __restrict__ ssrc) {
  int stride = gridDim.x * blockDim.x;
  for (int i = blockIdx.x * blockDim.x + threadIdx.x; i < TOT_E; i += stride) {
    int s, d;
    if (i < NEDGES) { s = src[i]; d = dst[i]; } else { s = i - NEDGES; d = s; }
    int pos = atomicAdd(&cur[d], 1);
    ssrc[pos] = s;
  }
}

// ---------------- casts / packing (f32 -> f16) ----------------
__global__ void k_cast4(const float* __restrict__ X, ushort* __restrict__ Xh, int total4) {
  int stride = gridDim.x * blockDim.x;
  for (int i = blockIdx.x * blockDim.x + threadIdx.x; i < total4; i += stride) {
    float4 v = *(const float4*)&X[i * 4];
    ushort4 o;
    o.x = f2h(v.x); o.y = f2h(v.y); o.z = f2h(v.z); o.w = f2h(v.w);
    *(ushort4*)&Xh[i * 4] = o;
  }
}

// Bpack[kf][nf][lane][8] = B[kf*32 + (lane>>4)*8 + i][nf*16 + (lane&15)]
__global__ void k_packB(const float* __restrict__ W, ushort* __restrict__ Bp,
                        int N, int NF, int total) {
  int idx = blockIdx.x * blockDim.x + threadIdx.x;
  if (idx >= total) return;
  int i = idx & 7;
  int lane = (idx >> 3) & 63;
  int rem = idx >> 9;
  int nf = rem % NF;
  int kf = rem / NF;
  int k = kf * 32 + (lane >> 4) * 8 + i;
  int col = nf * 16 + (lane & 15);
  float v = (col < N) ? W[(size_t)k * N + col] : 0.f;
  Bp[idx] = f2h(v);
}

// ---------------- register-resident-B MFMA GEMM (f16) + fused logits ----------------
template<int KF, int NFW, int CG, int HEADS, int NF_TOT>
__global__ __launch_bounds__(256, 2) void k_gemm_reg(
    const ushort* __restrict__ A, const ushort* __restrict__ Bp,
    ushort* __restrict__ H, const float* __restrict__ a_s, const float* __restrict__ a_d,
    float* __restrict__ al_s, float* __restrict__ al_d, int M, int N, int K) {
  int wave = (blockIdx.x * blockDim.x + threadIdx.x) >> 6;
  int lane = threadIdx.x & 63;
  int lg = lane >> 4;
  int lr = lane & 15;
  int total_waves = (gridDim.x * blockDim.x) >> 6;
  int wpc = total_waves / CG;
  int cg = wave / wpc;
  int mslot = wave - cg * wpc;
  if (cg >= CG) return;

  half8v b[KF][NFW];
#pragma unroll
  for (int kf = 0; kf < KF; ++kf)
#pragma unroll
    for (int n = 0; n < NFW; ++n)
      b[kf][n] = *(const half8v*)(Bp + ((size_t)(kf * NF_TOT + cg * NFW + n) * 64 + lane) * 8);

  float asc[NFW], adc[NFW];
#pragma unroll
  for (int n = 0; n < NFW; ++n) {
    int col = (cg * NFW + n) * 16 + lr;
    bool ok = col < N;
    asc[n] = ok ? a_s[col] : 0.f;
    adc[n] = ok ? a_d[col] : 0.f;
  }

  int nstrips = M >> 4;
  for (int strip = mslot; strip < nstrips; strip += wpc) {
    const ushort* arow = A + (size_t)(strip * 16 + lr) * K + lg * 8;
    half8v a[KF];
#pragma unroll
    for (int kf = 0; kf < KF; ++kf) a[kf] = *(const half8v*)(arow + kf * 32);
    f32x4 acc[NFW];
#pragma unroll
    for (int n = 0; n < NFW; ++n) acc[n] = (f32x4){0.f, 0.f, 0.f, 0.f};
#pragma unroll
    for (int kf = 0; kf < KF; ++kf)
#pragma unroll
      for (int n = 0; n < NFW; ++n)
        acc[n] = __builtin_amdgcn_mfma_f32_16x16x32_f16(a[kf], b[kf][n], acc[n], 0, 0, 0);

#pragma unroll
    for (int n = 0; n < NFW; ++n) {
      int col = (cg * NFW + n) * 16 + lr;
      if (col < N) {
#pragma unroll
        for (int r = 0; r < 4; ++r) {
          int row = strip * 16 + lg * 4 + r;
          H[(size_t)row * N + col] = f2h(acc[n][r]);
        }
      }
    }

    float ps[4], pd[4];
#pragma unroll
    for (int r = 0; r < 4; ++r) {
      float s = 0.f, d = 0.f;
#pragma unroll
      for (int n = 0; n < NFW; ++n) {
        s += acc[n][r] * asc[n];
        d += acc[n][r] * adc[n];
      }
      ps[r] = s; pd[r] = d;
    }
#pragma unroll
    for (int off = 1; off <= 8; off <<= 1)
#pragma unroll
      for (int t = 0; t < 4; ++t) {
        ps[t] += __shfl_xor(ps[t], off);
        pd[t] += __shfl_xor(pd[t], off);
      }
    if (lr < 4) {
      int row = strip * 16 + lg * 4 + lr;
      if (HEADS == 4) {
        al_s[row * 4 + cg] = ps[lr];
        al_d[row * 4 + cg] = pd[lr];
      } else {
        al_s[row] = ps[lr];
        al_d[row] = pd[lr];
      }
    }
  }
}

// ---------------- aggregation: wave per dst node ----------------
// layers 0/1: H=4, C=64, f16 data.
// pass A: 64-edge-parallel online softmax stats.
// pass B: per 64-edge chunk, stash {idx, (alpha,alpha) half2 per head} in LDS,
//         then dual-half gather with __hfma2 (2 values/op, no per-value cvt).
__global__ __launch_bounds__(256) void k_agg4(const ushort* __restrict__ hb,
    const float* __restrict__ al_s, const float* __restrict__ al_d,
    const int* __restrict__ offs, const int* __restrict__ ssrc,
    const float* __restrict__ bias, ushort* __restrict__ outb) {
  __shared__ int s_idx[4][64];
  __shared__ uint s_alp[4][256];
  int w = threadIdx.x >> 6;
  int wid = (blockIdx.x * blockDim.x + threadIdx.x) >> 6;
  if (wid >= NODES) return;
  int lane = threadIdx.x & 63;
  int beg = offs[wid], end = offs[wid + 1];
  float4 ald4 = *(const float4*)&al_d[wid * 4];

  // pass A: stats
  float m[4], s[4];
#pragma unroll
  for (int h = 0; h < 4; ++h) { m[h] = -1e30f; s[h] = 0.f; }
  for (int i = beg + lane; i < end; i += 64) {
    int sv = ssrc[i];
    float4 a4 = *(const float4*)&al_s[sv * 4];
    float z[4] = {lrelu(a4.x + ald4.x), lrelu(a4.y + ald4.y),
                  lrelu(a4.z + ald4.z), lrelu(a4.w + ald4.w)};
#pragma unroll
    for (int h = 0; h < 4; ++h) {
      if (z[h] > m[h]) { s[h] = s[h] * __expf(m[h] - z[h]) + 1.f; m[h] = z[h]; }
      else s[h] += __expf(z[h] - m[h]);
    }
  }
#pragma unroll
  for (int off = 1; off <= 32; off <<= 1) {
#pragma unroll
    for (int h = 0; h < 4; ++h) {
      float mo = __shfl_xor(m[h], off), so = __shfl_xor(s[h], off);
      float mn = fmaxf(m[h], mo);
      s[h] = s[h] * __expf(m[h] - mn) + so * __expf(mo - mn);
      m[h] = mn;
    }
  }
  float inv[4];
#pragma unroll
  for (int h = 0; h < 4; ++h) inv[h] = 1.f / s[h];

  // pass B
  int half = lane >> 5;      // edge parity
  int cl = lane & 31;        // channel octet (8 f16 channels)
  int hh = cl >> 3;          // head of this octet
  __half2 z2 = __float2half2_rn(0.f);
  __half2 acc2a[4] = {z2, z2, z2, z2};
  __half2 acc2b[4] = {z2, z2, z2, z2};

  for (int cb = beg; cb < end; cb += 64) {
    int cnt = min(64, end - cb);
    wave_lds_fence();  // prior chunk's reads complete before overwrite
    if (lane < cnt) {
      int sv = ssrc[cb + lane];
      float4 a4 = *(const float4*)&al_s[sv * 4];  // L1-hot from pass A
      U2H p0, p1, p2, p3;
      p0.h = __float2half2_rn(__expf(lrelu(a4.x + ald4.x) - m[0]) * inv[0]);
      p1.h = __float2half2_rn(__expf(lrelu(a4.y + ald4.y) - m[1]) * inv[1]);
      p2.h = __float2half2_rn(__expf(lrelu(a4.z + ald4.z) - m[2]) * inv[2]);
      p3.h = __float2half2_rn(__expf(lrelu(a4.w + ald4.w) - m[3]) * inv[3]);
      s_idx[w][lane] = sv;
      uint4 pk = make_uint4(p0.u, p1.u, p2.u, p3.u);
      *(uint4*)&s_alp[w][lane * 4] = pk;
    }
    wave_lds_fence();  // writes visible to all lanes of this wave
    int e = half;
    for (; e + 2 < cnt; e += 4) {
      int sv0 = s_idx[w][e], sv1 = s_idx[w][e + 2];
      U2H a0, a1;
      a0.u = s_alp[w][e * 4 + hh];
      a1.u = s_alp[w][(e + 2) * 4 + hh];
      uint4 hv0 = *(const uint4*)(hb + (size_t)sv0 * 256 + cl * 8);
      uint4 hv1 = *(const uint4*)(hb + (size_t)sv1 * 256 + cl * 8);
      U2H v;
      v.u = hv0.x; acc2a[0] = __hfma2(a0.h, v.h, acc2a[0]);
      v.u = hv0.y; acc2a[1] = __hfma2(a0.h, v.h, acc2a[1]);
      v.u = hv0.z; acc2a[2] = __hfma2(a0.h, v.h, acc2a[2]);
      v.u = hv0.w; acc2a[3] = __hfma2(a0.h, v.h, acc2a[3]);
      v.u = hv1.x; acc2b[0] = __hfma2(a1.h, v.h, acc2b[0]);
      v.u = hv1.y; acc2b[1] = __hfma2(a1.h, v.h, acc2b[1]);
      v.u = hv1.z; acc2b[2] = __hfma2(a1.h, v.h, acc2b[2]);
      v.u = hv1.w; acc2b[3] = __hfma2(a1.h, v.h, acc2b[3]);
    }
    for (; e < cnt; e += 2) {
      int sv = s_idx[w][e];
      U2H a0; a0.u = s_alp[w][e * 4 + hh];
      uint4 hv = *(const uint4*)(hb + (size_t)sv * 256 + cl * 8);
      U2H v;
      v.u = hv.x; acc2a[0] = __hfma2(a0.h, v.h, acc2a[0]);
      v.u = hv.y; acc2a[1] = __hfma2(a0.h, v.h, acc2a[1]);
      v.u = hv.z; acc2a[2] = __hfma2(a0.h, v.h, acc2a[2]);
      v.u = hv.w; acc2a[3] = __hfma2(a0.h, v.h, acc2a[3]);
    }
  }
  // merge dual accumulators, then cross-half reduce
  ushort4 ores[2];
#pragma unroll
  for (int j = 0; j < 4; ++j) {
    U2H t; t.h = __hadd2(acc2a[j], acc2b[j]);
    U2H o; o.u = __shfl_xor(t.u, 32);
    t.h = __hadd2(t.h, o.h);
    float lo = __low2float(t.h) + bias[cl * 16 / 2 + j * 2];      // cl*8 + 2j
    float hi = __high2float(t.h) + bias[cl * 8 + j * 2 + 1];
    lo = lo > 0.f ? lo : __expf(lo) - 1.f;
    hi = hi > 0.f ? hi : __expf(hi) - 1.f;
    ((ushort*)ores)[j * 2]     = f2h(lo);
    ((ushort*)ores)[j * 2 + 1] = f2h(hi);
  }
  if (half == 0) {
    *(ushort4*)(outb + (size_t)wid * 256 + cl * 8)     = ores[0];
    *(ushort4*)(outb + (size_t)wid * 256 + cl * 8 + 4) = ores[1];
  }
}

// layer 2: H=1, C=40, f16; edge-quad gather with __hfma2
__global__ __launch_bounds__(256) void k_agg1(const ushort* __restrict__ hb,
    const float* __restrict__ al_s, const float* __restrict__ al_d,
    const int* __restrict__ offs, const int* __restrict__ ssrc,
    const float* __restrict__ bias, float* __restrict__ out) {
  __shared__ int s_idx[4][64];
  __shared__ uint s_alp[4][64];
  int w = threadIdx.x >> 6;
  int wid = (blockIdx.x * blockDim.x + threadIdx.x) >> 6;
  if (wid >= NODES) return;
  int lane = threadIdx.x & 63;
  int beg = offs[wid], end = offs[wid + 1];
  float ald = al_d[wid];

  float m = -1e30f, s = 0.f;
  for (int i = beg + lane; i < end; i += 64) {
    float z = lrelu(al_s[ssrc[i]] + ald);
    if (z > m) { s = s * __expf(m - z) + 1.f; m = z; }
    else s += __expf(z - m);
  }
#pragma unroll
  for (int off = 1; off <= 32; off <<= 1) {
    float mo = __shfl_xor(m, off), so = __shfl_xor(s, off);
    float mn = fmaxf(m, mo);
    s = s * __expf(m - mn) + so * __expf(mo - mn);
    m = mn;
  }
  float inv = 1.f / s;

  int q = lane >> 4;         // edge quad
  int cq = lane & 15;        // channel quad (4 f16 channels)
  bool act = cq < 10;
  __half2 z2 = __float2half2_rn(0.f);
  __half2 acc2a[2] = {z2, z2};
  __half2 acc2b[2] = {z2, z2};
  for (int cb = beg; cb < end; cb += 64) {
    int cnt = min(64, end - cb);
    wave_lds_fence();
    if (lane < cnt) {
      int sv = ssrc[cb + lane];
      U2H p; p.h = __float2half2_rn(__expf(lrelu(al_s[sv] + ald) - m) * inv);
      s_idx[w][lane] = sv;
      s_alp[w][lane] = p.u;
    }
    wave_lds_fence();
    int e = q;
    for (; e + 4 < cnt; e += 8) {
      int sv0 = s_idx[w][e], sv1 = s_idx[w][e + 4];
      U2H a0, a1;
      a0.u = s_alp[w][e];
      a1.u = s_alp[w][e + 4];
      if (act) {
        uint2 hv0 = *(const uint2*)(hb + (size_t)sv0 * 40 + cq * 4);
        uint2 hv1 = *(const uint2*)(hb + (size_t)sv1 * 40 + cq * 4);
        U2H v;
        v.u = hv0.x; acc2a[0] = __hfma2(a0.h, v.h, acc2a[0]);
        v.u = hv0.y; acc2a[1] = __hfma2(a0.h, v.h, acc2a[1]);
        v.u = hv1.x; acc2b[0] = __hfma2(a1.h, v.h, acc2b[0]);
        v.u = hv1.y; acc2b[1] = __hfma2(a1.h, v.h, acc2b[1]);
      }
    }
    for (; e < cnt; e += 4) {
      int sv = s_idx[w][e];
      U2H a0; a0.u = s_alp[w][e];
      if (act) {
        uint2 hv = *(const uint2*)(hb + (size_t)sv * 40 + cq * 4);
        U2H v;
        v.u = hv.x; acc2a[0] = __hfma2(a0.h, v.h, acc2a[0]);
        v.u = hv.y; acc2a[1] = __hfma2(a0.h, v.h, acc2a[1]);
      }
    }
  }
  float vv[4];
#pragma unroll
  for (int j = 0; j < 2; ++j) {
    U2H t; t.h = __hadd2(acc2a[j], acc2b[j]);
    U2H o;
    o.u = __shfl_xor(t.u, 16); t.h = __hadd2(t.h, o.h);
    o.u = __shfl_xor(t.u, 32); t.h = __hadd2(t.h, o.h);
    vv[j * 2]     = __low2float(t.h);
    vv[j * 2 + 1] = __high2float(t.h);
  }
  float mm = -1e30f;
  if (act) {
#pragma unroll
    for (int j = 0; j < 4; ++j) {
      vv[j] += bias[cq * 4 + j];
      mm = fmaxf(mm, vv[j]);
    }
  }
#pragma unroll
  for (int off = 1; off <= 8; off <<= 1) mm = fmaxf(mm, __shfl_xor(mm, off));
  float se = 0.f;
  if (act) {
#pragma unroll
    for (int j = 0; j < 4; ++j) se += __expf(vv[j] - mm);
  }
#pragma unroll
  for (int off = 1; off <= 8; off <<= 1) se += __shfl_xor(se, off);
  if (act && q == 0) {
    float lse = mm + __logf(se);
    float4 o;
    o.x = vv[0] - lse; o.y = vv[1] - lse; o.z = vv[2] - lse; o.w = vv[3] - lse;
    *(float4*)&out[(size_t)wid * 40 + cq * 4] = o;
  }
}

// ---------------- launch ----------------
extern "C" void kernel_launch(void* const* d_in, const int* in_sizes, int n_in,
                              void* d_out, int out_size, void* d_ws, size_t ws_size,
                              hipStream_t stream) {
  const float* x   = (const float*)d_in[0];
  const int*   ei  = (const int*)d_in[1];
  const float* W0  = (const float*)d_in[2];
  const float* as0 = (const float*)d_in[3];
  const float* ad0 = (const float*)d_in[4];
  const float* b0  = (const float*)d_in[5];
  const float* W1  = (const float*)d_in[6];
  const float* as1 = (const float*)d_in[7];
  const float* ad1 = (const float*)d_in[8];
  const float* b1  = (const float*)d_in[9];
  const float* W2  = (const float*)d_in[10];
  const float* as2 = (const float*)d_in[11];
  const float* ad2 = (const float*)d_in[12];
  const float* b2  = (const float*)d_in[13];
  float* out = (float*)d_out;

  char* p = (char*)d_ws;
  auto take = [&](size_t bytes) {
    char* q = p;
    p += (bytes + 255) & ~(size_t)255;
    return (void*)q;
  };
  ushort* xb0 = (ushort*)take((size_t)NODES * 128 * 2);
  ushort* xb1 = (ushort*)take((size_t)NODES * 256 * 2);
  ushort* xb2 = (ushort*)take((size_t)NODES * 256 * 2);
  ushort* hb  = (ushort*)take((size_t)NODES * 256 * 2);
  float* als  = (float*)take((size_t)NODES * 4 * 4);
  float* ald  = (float*)take((size_t)NODES * 4 * 4);
  int* ssrc   = (int*)take((size_t)TOT_E * 4);
  int* offs   = (int*)take((size_t)(NODES + 1) * 4);
  int* cur    = (int*)take((size_t)NODES * 4);
  int* cnt    = (int*)take((size_t)NODES * 4);
  int* bsum   = (int*)take((size_t)SCAN_NB * 4);
  int* bpre   = (int*)take((size_t)SCAN_NB * 4);
  ushort* Bp0 = (ushort*)take((size_t)4 * 16 * 512 * 2);
  ushort* Bp1 = (ushort*)take((size_t)8 * 16 * 512 * 2);
  ushort* Bp2 = (ushort*)take((size_t)8 * 3 * 512 * 2);

  // CSR build (dst-sorted edge list incl. self-loops)
  hipMemsetAsync(cnt, 0, (size_t)NODES * 4, stream);
  k_hist<<<2048, 256, 0, stream>>>(ei + NEDGES, cnt);
  k_scan_red<<<SCAN_NB, SCAN_B, 0, stream>>>(cnt, bsum);
  k_scan_part<<<1, 256, 0, stream>>>(bsum, bpre);
  k_scan_emit<<<SCAN_NB, SCAN_B, 0, stream>>>(cnt, bpre, offs, cur);
  k_scatter<<<2048, 256, 0, stream>>>(ei, ei + NEDGES, cur, ssrc);

  // f16 casts / weight packs
  k_cast4<<<2048, 256, 0, stream>>>(x, xb0, NODES * 128 / 4);
  {
    int t0 = 4 * 16 * 512;  k_packB<<<(t0 + 255) / 256, 256, 0, stream>>>(W0, Bp0, 256, 16, t0);
    int t1 = 8 * 16 * 512;  k_packB<<<(t1 + 255) / 256, 256, 0, stream>>>(W1, Bp1, 256, 16, t1);
    int t2 = 8 * 3 * 512;   k_packB<<<(t2 + 255) / 256, 256, 0, stream>>>(W2, Bp2, 40, 3, t2);
  }

  int nwb = (NODES * 64 + 255) / 256;       // wave-per-node blocks
  int ggb = 512;                            // gemm grid: 2048 waves

  // layer 0
  k_gemm_reg<4, 4, 4, 4, 16><<<ggb, 256, 0, stream>>>(xb0, Bp0, hb, as0, ad0, als, ald, NODES, 256, 128);
  k_agg4<<<nwb, 256, 0, stream>>>(hb, als, ald, offs, ssrc, b0, xb1);

  // layer 1
  k_gemm_reg<8, 4, 4, 4, 16><<<ggb, 256, 0, stream>>>(xb1, Bp1, hb, as1, ad1, als, ald, NODES, 256, 256);
  k_agg4<<<nwb, 256, 0, stream>>>(hb, als, ald, offs, ssrc, b1, xb2);

  // layer 2
  k_gemm_reg<8, 3, 1, 1, 3><<<ggb, 256, 0, stream>>>(xb2, Bp2, hb, as2, ad2, als, ald, NODES, 40, 256);
  k_agg1<<<nwb, 256, 0, stream>>>(hb, als, ald, offs, ssrc, b2, out);
}